// Round 9
// baseline (207.845 us; speedup 1.0000x reference)
//
#include <hip/hip_runtime.h>

// DenseLayerWithComplexNeurons: out = per-cell-type-MLP( x @ W^T + b )
// M = B*S = 8192, K = DIN = 1024, N = A*DOUT = 4096, DOUT = 1024
// T = 4 cell types, G = 256 neurons/type, A = 4, H = 8.
//
// Round 3: 256x128 BK=64 2-barrier loop. 101.6 us (MfmaUtil 29%).
// Rounds 4-7,11: pipeline attempts (counted vmcnt / raw barriers / 3-buf):
//   134/118/FAIL/113/117 us -- ALL lose to plain __syncthreads versions.
//   CLOSED: source-level waitcnt control regresses codegen here (guide
//   m131-m141); compiler's own scheduling around __syncthreads wins.
// Round 8: launch_bounds(256,3): acc spills. 113.5 us. 128 acc floats/thread
//   means 2 waves/SIMD max -- occupancy is register-structural.
// Round 9: BK=32 double-buffer, stage(t+1)->compute(t)->syncthreads. 97.4 us.
// Round 10: lane-local epilogue via W-row permutation (zero-LDS epilogue).
//   96.6 us. Budget: MFMA 29us (34 cyc/SIMD each), LDS 20us, VALU ~7us ->
//   ~46us = both resident 4-wave barrier groups stalled SIMULTANEOUSLY.
// Round 12: same per-wave kernel, BM 256->128 with 2-WAVE blocks: 4
//   independent barrier groups/CU (was 2). Per-CU ds_read/MFMA totals
//   unchanged; stalls desynchronize across 4 groups; barriers join 2 waves
//   not 4. Pure TLP-granularity change, no sync-structure novelty.

typedef __bf16 bf16x8 __attribute__((ext_vector_type(8)));
typedef float f32x4 __attribute__((ext_vector_type(4)));
typedef float f32x16 __attribute__((ext_vector_type(16)));

#define BM 128
#define BN 128
#define BK 32
#define KDIM 1024
#define NT 32                        // K / BK
#define ABUF 8192                    // A bytes per buffer (128 rows x 32 k x 2B)
#define BUFB 16384                   // per-buffer bytes: A 8K + B 8K
#define XN8 (8192 * 1024 / 8)
#define WN8 (4096 * 1024 / 8)

__global__ __launch_bounds__(256) void cvt_bf16_kernel(
    const float* __restrict__ x, const float* __restrict__ w,
    __bf16* __restrict__ xb, __bf16* __restrict__ wb) {
    int i = blockIdx.x * 256 + threadIdx.x;
    const float* src;
    __bf16* dst;
    int j, jdst;
    if (i < XN8) { src = x; dst = xb; j = i; jdst = i; }
    else {
        src = w; dst = wb; j = i - XN8;
        // W row permutation: row r = 4q+a  ->  128*(q>>5) + 32*a + (q&31)
        const int r  = j >> 7;          // 1024 cols = 128 chunks of 8
        const int c8 = j & 127;
        const int q  = r >> 2;
        const int a  = r & 3;
        const int rn = ((q >> 5) << 7) + (a << 5) + (q & 31);
        jdst = (rn << 7) + c8;
    }
    const f32x4* p = (const f32x4*)src + 2 * (size_t)j;
    f32x4 a = p[0], b = p[1];
    bf16x8 o;
    o[0] = (__bf16)a[0]; o[1] = (__bf16)a[1]; o[2] = (__bf16)a[2]; o[3] = (__bf16)a[3];
    o[4] = (__bf16)b[0]; o[5] = (__bf16)b[1]; o[6] = (__bf16)b[2]; o[7] = (__bf16)b[3];
    ((bf16x8*)dst)[jdst] = o;
}

__global__ __launch_bounds__(128, 2) void fused_gemm_mlp_kernel(
    const __bf16* __restrict__ Ag,   // [8192][1024] bf16 (x)
    const __bf16* __restrict__ Bg,   // [4096][1024] bf16 (perm'd weight, B^T layout)
    const float* __restrict__ bias,  // [4096] (original order)
    const float* __restrict__ cw1,   // [4][4][8]
    const float* __restrict__ cb1,   // [4][8]
    const float* __restrict__ cw2,   // [4][8]
    const float* __restrict__ cb2,   // [4]
    float* __restrict__ out)         // [8192][1024]
{
    __shared__ __align__(16) unsigned char raw[2 * BUFB];   // 32768 B

    const int tid  = threadIdx.x;
    const int wave = tid >> 6;       // 0..1 = m half (64 rows each)
    const int lane = tid & 63;
    const int wm = wave;
    const int bn0 = blockIdx.x * BN; // n offset in [0,4096)
    const int bm0 = blockIdx.y * BM; // m offset in [0,8192)

    f32x16 acc[2][4] = {};           // 2 m-tiles x 4 a-subtiles of 32x32

    // ---- staging lane mapping (row-pair physical rows; verified R9/R10) ----
    // 1KB DMA chunk = 16 rows (8 row-pairs x 128B). Lane i writes byte 16*i:
    // q_loc=i>>3, slot=i&7; source: s_log=slot^q_loc, row=2q_loc+(s_log>>2),
    // col16=s_log&3. Global (R,c) lands at chunk*1024 + ((R>>1)&7)*128 +
    // (((R&1)*4+c)^((R>>1)&7))*16 == fragment address below.
    const int qloc = lane >> 3;
    const int slog = (lane & 7) ^ qloc;
    const int arow = 2 * qloc + (slog >> 2);
    const int acol = (slog & 3) * 8;

    // ---- fragment LDS byte addresses (buffer-relative; verified R10) ----
    // MFMA 32x32x16: row = lane&31, k = kh*16 + (lane>>5)*8 + i.
    // A row = wm*64 + mi*32 + lr5 -> wm*4096 + mi*2048 + lrh*128 + slot
    // B row = a*32 + lr5          -> ABUF + a*2048 + lrh*128 + slot
    const int lr5 = lane & 31;
    const int lk2 = lane >> 5;   // 0..1
    const int lrh = lr5 >> 1;    // 0..15
    const int lp  = lr5 & 1;
    int a_addr[2], b_addr[2];
#pragma unroll
    for (int kh = 0; kh < 2; ++kh) {
        const int slot = (((lp * 4) + (kh * 2 + lk2)) ^ (lrh & 7)) * 16;
        a_addr[kh] = wm * 4096 + lrh * 128 + slot;
        b_addr[kh] = ABUF + lrh * 128 + slot;
    }
    const char* sb = (const char*)raw;

    // ---- stage one BK=32 tile t into buffer (t&1): 16 chunks, 8 per wave ----
    auto stage = [&](int t) {
        const int bb = (t & 1) * BUFB;
        const int k0 = t * BK;
#pragma unroll
        for (int c = 0; c < 4; ++c) {          // A: 8 chunks of 16 rows
            const int ch = wave + c * 2;
            const __bf16* g = Ag + (size_t)(bm0 + ch * 16 + arow) * KDIM + k0 + acol;
            __builtin_amdgcn_global_load_lds(
                (__attribute__((address_space(1))) void*)g,
                (__attribute__((address_space(3))) void*)&raw[bb + ch * 1024],
                16, 0, 0);
        }
#pragma unroll
        for (int c = 0; c < 4; ++c) {          // B: 8 chunks of 16 rows
            const int ch = wave + c * 2;
            const __bf16* g = Bg + (size_t)(bn0 + ch * 16 + arow) * KDIM + k0 + acol;
            __builtin_amdgcn_global_load_lds(
                (__attribute__((address_space(1))) void*)g,
                (__attribute__((address_space(3))) void*)&raw[bb + ABUF + ch * 1024],
                16, 0, 0);
        }
    };

    // ---- prologue: tile 0 staged and drained ----
    stage(0);
    __syncthreads();

    // ---- main loop: stage(t+1) -> compute(t) -> barrier (verified R9/R10) ----
    for (int t = 0; t < NT; ++t) {
        if (t + 1 < NT) stage(t + 1);

        const int cb = (t & 1) * BUFB;
#pragma unroll
        for (int kh = 0; kh < 2; ++kh) {
            bf16x8 af[2], bfr[4];
#pragma unroll
            for (int mi = 0; mi < 2; ++mi)
                af[mi] = *(const bf16x8*)(sb + cb + a_addr[kh] + mi * 2048);
#pragma unroll
            for (int a = 0; a < 4; ++a)
                bfr[a] = *(const bf16x8*)(sb + cb + b_addr[kh] + a * 2048);
#pragma unroll
            for (int mi = 0; mi < 2; ++mi)
#pragma unroll
                for (int a = 0; a < 4; ++a)
                    acc[mi][a] = __builtin_amdgcn_mfma_f32_32x32x16_bf16(
                        af[mi], bfr[a], acc[mi][a], 0, 0, 0);
        }
        __syncthreads();
    }

    // ---- epilogue: fully lane-local per-neuron MLP (verified R10) ----
    // Lane (lr5) owns neuron q = bn0/4 + lr5; acc[mi][a][g] = z(row, 4q+a)
    // with row = wm*64 + mi*32 + (g&3) + 8*(g>>2) + 4*lk2.
    const int tct = bn0 >> 10;  // cell type, block-uniform
    float w1[32], b1[8], w2[8];
#pragma unroll
    for (int i = 0; i < 32; ++i) w1[i] = cw1[tct * 32 + i];
#pragma unroll
    for (int i = 0; i < 8; ++i) { b1[i] = cb1[tct * 8 + i]; w2[i] = cw2[tct * 8 + i]; }
    const float b2 = cb2[tct];

    const f32x4 bz = *(const f32x4*)&bias[bn0 + 4 * lr5];   // components a=0..3

    const float L2E2 = 2.885390081777927f;  // 2*log2(e)
    float* outp = out + (size_t)(bm0 + wm * 64 + 4 * lk2) * 1024 + (bn0 >> 2) + lr5;

#pragma unroll
    for (int mi = 0; mi < 2; ++mi) {
#pragma unroll
        for (int g = 0; g < 16; ++g) {
            const float z0 = acc[mi][0][g] + bz[0];
            const float z1 = acc[mi][1][g] + bz[1];
            const float z2 = acc[mi][2][g] + bz[2];
            const float z3 = acc[mi][3][g] + bz[3];
            float o = 0.f;
#pragma unroll
            for (int hh = 0; hh < 8; ++hh) {
                float pre = z0 * w1[0 * 8 + hh] + z1 * w1[1 * 8 + hh]
                          + z2 * w1[2 * 8 + hh] + z3 * w1[3 * 8 + hh] + b1[hh];
                float e = __builtin_amdgcn_exp2f(pre * L2E2);        // e^(2*pre)
                float th = 1.0f - 2.0f * __builtin_amdgcn_rcpf(e + 1.0f);
                o += th * w2[hh];
            }
            o += b2;
            const int row = mi * 32 + (g & 3) + 8 * (g >> 2);  // + wm*64 + 4*lk2 in outp
            outp[(size_t)row * 1024] = o;
        }
    }
}

extern "C" void kernel_launch(void* const* d_in, const int* in_sizes, int n_in,
                              void* d_out, int out_size, void* d_ws, size_t ws_size,
                              hipStream_t stream) {
    const float* x    = (const float*)d_in[0];
    const float* w    = (const float*)d_in[1];
    const float* bias = (const float*)d_in[2];
    const float* cw1  = (const float*)d_in[3];
    const float* cb1  = (const float*)d_in[4];
    const float* cw2  = (const float*)d_in[5];
    const float* cb2  = (const float*)d_in[6];
    float* out = (float*)d_out;

    __bf16* xb = (__bf16*)d_ws;                       // 8192*1024 bf16 = 16 MB
    __bf16* wb = xb + (size_t)8192 * 1024;            // 4096*1024 bf16 = 8 MB

    cvt_bf16_kernel<<<(XN8 + WN8) / 256, 256, 0, stream>>>(x, w, xb, wb);

    dim3 grid(4096 / BN, 8192 / BM);  // (32, 64)
    fused_gemm_mlp_kernel<<<grid, 128, 0, stream>>>(xb, wb, bias, cw1, cb1, cw2, cb2, out);
}

// Round 10
// 195.165 us; speedup vs baseline: 1.0650x; 1.0650x over previous
//
#include <hip/hip_runtime.h>

// DenseLayerWithComplexNeurons: out = per-cell-type-MLP( x @ W^T + b )
// M = B*S = 8192, K = DIN = 1024, N = A*DOUT = 4096, DOUT = 1024
// T = 4 cell types, G = 256 neurons/type, A = 4, H = 8.
//
// Round 3: 256x128 BK=64 2-barrier loop. 101.6 us (MfmaUtil 29%).
// Rounds 4-7,11: pipeline attempts (counted vmcnt / raw barriers / 3-buf):
//   134/118/FAIL/113/117 us -- ALL lose to plain __syncthreads versions.
//   CLOSED: compiler's own scheduling around __syncthreads wins here.
// Round 8: launch_bounds(256,3) on 128-acc waves: acc spills. 113.5 us.
// Round 9: BK=32 dbuf, stage(t+1)->compute(t)->syncthreads. 97.4 us.
// Round 10: lane-local epilogue via W-row permutation. 96.6 us.
//   Budget: MFMA 29us, LDS ~20us, wall 96us -> latency-bound.
// Round 12: 2-wave blocks, same 220 regs/wave: occupancy UNCHANGED-worse
//   (16%), 126 us. Occupancy is purely register-capped: 92 arch VGPR +
//   128 AGPR acc = 220 -> 2 waves/SIMD at the 512-reg/SIMD pool.
// Round 13: shrink acc. BM=128, 4 waves/block, per-wave tile 32x128:
//   acc[4] f32x16 = 64 AGPR -> ~150 total regs -> 3 waves/SIMD =
//   12 waves/CU = 3 blocks (LDS 96K). launch_bounds(256,3) caps at 170
//   (acc cannot spill). Lane-local epilogue unchanged (wave spans all
//   4 arity subtiles). B frags read 4x/block (LDS ~25us, still < MFMA).

typedef __bf16 bf16x8 __attribute__((ext_vector_type(8)));
typedef float f32x4 __attribute__((ext_vector_type(4)));
typedef float f32x16 __attribute__((ext_vector_type(16)));

#define BM 128
#define BN 128
#define BK 32
#define KDIM 1024
#define NT 32                        // K / BK
#define ABUF 8192                    // A bytes per buffer (128 rows x 32 k x 2B)
#define BUFB 16384                   // per-buffer bytes: A 8K + B 8K
#define XN8 (8192 * 1024 / 8)
#define WN8 (4096 * 1024 / 8)

__global__ __launch_bounds__(256) void cvt_bf16_kernel(
    const float* __restrict__ x, const float* __restrict__ w,
    __bf16* __restrict__ xb, __bf16* __restrict__ wb) {
    int i = blockIdx.x * 256 + threadIdx.x;
    const float* src;
    __bf16* dst;
    int j, jdst;
    if (i < XN8) { src = x; dst = xb; j = i; jdst = i; }
    else {
        src = w; dst = wb; j = i - XN8;
        // W row permutation: row r = 4q+a  ->  128*(q>>5) + 32*a + (q&31)
        const int r  = j >> 7;          // 1024 cols = 128 chunks of 8
        const int c8 = j & 127;
        const int q  = r >> 2;
        const int a  = r & 3;
        const int rn = ((q >> 5) << 7) + (a << 5) + (q & 31);
        jdst = (rn << 7) + c8;
    }
    const f32x4* p = (const f32x4*)src + 2 * (size_t)j;
    f32x4 a = p[0], b = p[1];
    bf16x8 o;
    o[0] = (__bf16)a[0]; o[1] = (__bf16)a[1]; o[2] = (__bf16)a[2]; o[3] = (__bf16)a[3];
    o[4] = (__bf16)b[0]; o[5] = (__bf16)b[1]; o[6] = (__bf16)b[2]; o[7] = (__bf16)b[3];
    ((bf16x8*)dst)[jdst] = o;
}

__global__ __launch_bounds__(256, 3) void fused_gemm_mlp_kernel(
    const __bf16* __restrict__ Ag,   // [8192][1024] bf16 (x)
    const __bf16* __restrict__ Bg,   // [4096][1024] bf16 (perm'd weight, B^T layout)
    const float* __restrict__ bias,  // [4096] (original order)
    const float* __restrict__ cw1,   // [4][4][8]
    const float* __restrict__ cb1,   // [4][8]
    const float* __restrict__ cw2,   // [4][8]
    const float* __restrict__ cb2,   // [4]
    float* __restrict__ out)         // [8192][1024]
{
    __shared__ __align__(16) unsigned char raw[2 * BUFB];   // 32768 B

    const int tid  = threadIdx.x;
    const int wave = tid >> 6;       // 0..3 = m quarter (32 rows each)
    const int lane = tid & 63;
    const int bn0 = blockIdx.x * BN; // n offset in [0,4096)
    const int bm0 = blockIdx.y * BM; // m offset in [0,8192)

    f32x16 acc[4] = {};              // 4 a-subtiles of 32x32 (one 32-row strip)

    // ---- staging lane mapping (row-pair physical rows; verified R9/R10) ----
    // 1KB DMA chunk = 16 rows (8 row-pairs x 128B). Lane i writes byte 16*i:
    // q_loc=i>>3, slot=i&7; source: s_log=slot^q_loc, row=2q_loc+(s_log>>2),
    // col16=s_log&3. Global (R,c) lands at chunk*1024 + ((R>>1)&7)*128 +
    // (((R&1)*4+c)^((R>>1)&7))*16 == fragment address below.
    const int qloc = lane >> 3;
    const int slog = (lane & 7) ^ qloc;
    const int arow = 2 * qloc + (slog >> 2);
    const int acol = (slog & 3) * 8;

    // ---- fragment LDS byte addresses (buffer-relative) ----
    // MFMA 32x32x16: row = lane&31, k = kh*16 + (lane>>5)*8 + i.
    // A row = wave*32 + lr5 -> wave*2048 + lrh*128 + slot
    // B row = a*32 + lr5    -> ABUF + a*2048 + lrh*128 + slot
    const int lr5 = lane & 31;
    const int lk2 = lane >> 5;   // 0..1
    const int lrh = lr5 >> 1;    // 0..15
    const int lp  = lr5 & 1;
    int a_addr[2], b_addr[2];
#pragma unroll
    for (int kh = 0; kh < 2; ++kh) {
        const int slot = (((lp * 4) + (kh * 2 + lk2)) ^ (lrh & 7)) * 16;
        a_addr[kh] = wave * 2048 + lrh * 128 + slot;
        b_addr[kh] = ABUF + lrh * 128 + slot;
    }
    const char* sb = (const char*)raw;

    // ---- stage one BK=32 tile t into buffer (t&1): 16 chunks, 4 per wave ----
    auto stage = [&](int t) {
        const int bb = (t & 1) * BUFB;
        const int k0 = t * BK;
#pragma unroll
        for (int c = 0; c < 2; ++c) {          // A: 8 chunks of 16 rows
            const int ch = wave + c * 4;
            const __bf16* g = Ag + (size_t)(bm0 + ch * 16 + arow) * KDIM + k0 + acol;
            __builtin_amdgcn_global_load_lds(
                (__attribute__((address_space(1))) void*)g,
                (__attribute__((address_space(3))) void*)&raw[bb + ch * 1024],
                16, 0, 0);
        }
#pragma unroll
        for (int c = 0; c < 2; ++c) {          // B: 8 chunks of 16 rows
            const int ch = wave + c * 4;
            const __bf16* g = Bg + (size_t)(bn0 + ch * 16 + arow) * KDIM + k0 + acol;
            __builtin_amdgcn_global_load_lds(
                (__attribute__((address_space(1))) void*)g,
                (__attribute__((address_space(3))) void*)&raw[bb + ABUF + ch * 1024],
                16, 0, 0);
        }
    };

    // ---- prologue: tile 0 staged and drained ----
    stage(0);
    __syncthreads();

    // ---- main loop: stage(t+1) -> compute(t) -> barrier (verified R9/R10) ----
    for (int t = 0; t < NT; ++t) {
        if (t + 1 < NT) stage(t + 1);

        const int cb = (t & 1) * BUFB;
#pragma unroll
        for (int kh = 0; kh < 2; ++kh) {
            bf16x8 af, bfr[4];
            af = *(const bf16x8*)(sb + cb + a_addr[kh]);
#pragma unroll
            for (int a = 0; a < 4; ++a)
                bfr[a] = *(const bf16x8*)(sb + cb + b_addr[kh] + a * 2048);
#pragma unroll
            for (int a = 0; a < 4; ++a)
                acc[a] = __builtin_amdgcn_mfma_f32_32x32x16_bf16(
                    af, bfr[a], acc[a], 0, 0, 0);
        }
        __syncthreads();
    }

    // ---- epilogue: fully lane-local per-neuron MLP (verified R10) ----
    // Lane (lr5) owns neuron q = bn0/4 + lr5; acc[a][g] = z(row, 4q+a)
    // with row = wave*32 + (g&3) + 8*(g>>2) + 4*lk2.
    const int tct = bn0 >> 10;  // cell type, block-uniform
    float w1[32], b1[8], w2[8];
#pragma unroll
    for (int i = 0; i < 32; ++i) w1[i] = cw1[tct * 32 + i];
#pragma unroll
    for (int i = 0; i < 8; ++i) { b1[i] = cb1[tct * 8 + i]; w2[i] = cw2[tct * 8 + i]; }
    const float b2 = cb2[tct];

    const f32x4 bz = *(const f32x4*)&bias[bn0 + 4 * lr5];   // components a=0..3

    const float L2E2 = 2.885390081777927f;  // 2*log2(e)
    float* outp = out + (size_t)(bm0 + wave * 32 + 4 * lk2) * 1024 + (bn0 >> 2) + lr5;

#pragma unroll
    for (int g = 0; g < 16; ++g) {
        const float z0 = acc[0][g] + bz[0];
        const float z1 = acc[1][g] + bz[1];
        const float z2 = acc[2][g] + bz[2];
        const float z3 = acc[3][g] + bz[3];
        float o = 0.f;
#pragma unroll
        for (int hh = 0; hh < 8; ++hh) {
            float pre = z0 * w1[0 * 8 + hh] + z1 * w1[1 * 8 + hh]
                      + z2 * w1[2 * 8 + hh] + z3 * w1[3 * 8 + hh] + b1[hh];
            float e = __builtin_amdgcn_exp2f(pre * L2E2);        // e^(2*pre)
            float th = 1.0f - 2.0f * __builtin_amdgcn_rcpf(e + 1.0f);
            o += th * w2[hh];
        }
        o += b2;
        const int row = (g & 3) + 8 * (g >> 2);  // + wave*32 + 4*lk2 in outp
        outp[(size_t)row * 1024] = o;
    }
}

extern "C" void kernel_launch(void* const* d_in, const int* in_sizes, int n_in,
                              void* d_out, int out_size, void* d_ws, size_t ws_size,
                              hipStream_t stream) {
    const float* x    = (const float*)d_in[0];
    const float* w    = (const float*)d_in[1];
    const float* bias = (const float*)d_in[2];
    const float* cw1  = (const float*)d_in[3];
    const float* cb1  = (const float*)d_in[4];
    const float* cw2  = (const float*)d_in[5];
    const float* cb2  = (const float*)d_in[6];
    float* out = (float*)d_out;

    __bf16* xb = (__bf16*)d_ws;                       // 8192*1024 bf16 = 16 MB
    __bf16* wb = xb + (size_t)8192 * 1024;            // 4096*1024 bf16 = 8 MB

    cvt_bf16_kernel<<<(XN8 + WN8) / 256, 256, 0, stream>>>(x, w, xb, wb);

    dim3 grid(4096 / BN, 8192 / BM);  // (32, 64)
    fused_gemm_mlp_kernel<<<grid, 256, 0, stream>>>(xb, wb, bias, cw1, cb1, cw2, cb2, out);
}